// Round 1
// baseline (654.479 us; speedup 1.0000x reference)
//
#include <hip/hip_runtime.h>
#include <hip/hip_bf16.h>

#define EPS 1e-5f

typedef __attribute__((ext_vector_type(8))) short bf16x8;
typedef __attribute__((ext_vector_type(4))) float f32x4;
typedef __attribute__((ext_vector_type(4))) short s16x4;

__device__ __forceinline__ float b2f(ushort u) {
    union { uint i; float f; } v; v.i = ((uint)u) << 16; return v.f;
}
__device__ __forceinline__ ushort f2b(float f) {  // RNE f32->bf16
    uint x = __float_as_uint(f);
    return (ushort)((x + 0x7fffu + ((x >> 16) & 1u)) >> 16);
}

// ---------------- weight prep ----------------
__global__ void k_fold_conv1(const float* __restrict__ w, const float* __restrict__ cb,
                             const float* __restrict__ g, const float* __restrict__ be,
                             const float* __restrict__ mn, const float* __restrict__ vr,
                             ushort* __restrict__ Wf, float* __restrict__ bf) {
    int i = blockIdx.x * 256 + threadIdx.x;   // 65536 = 256x256
    int o = i >> 8;
    float inv = g[o] * rsqrtf(vr[o] + EPS);
    Wf[i] = f2b(w[i] * inv);
    if ((i & 255) == 0) bf[o] = cb[o] * inv + be[o] - mn[o] * inv;
}

__global__ void k_fold_dw(const float* __restrict__ w, const float* __restrict__ cb,
                          const float* __restrict__ g, const float* __restrict__ be,
                          const float* __restrict__ mn, const float* __restrict__ vr,
                          float* __restrict__ wT, float* __restrict__ bf) {
    int i = blockIdx.x * 256 + threadIdx.x;
    if (i < 2304) {                           // 256 ch x 9 taps
        int c = i / 9, k = i % 9;
        float inv = g[c] * rsqrtf(vr[c] + EPS);
        wT[k * 256 + c] = w[i] * inv;         // transposed [9][256] for vector reads
    }
    if (i < 256) {
        float inv = g[i] * rsqrtf(vr[i] + EPS);
        bf[i] = cb[i] * inv + be[i] - mn[i] * inv;
    }
}

__global__ void k_cvt_bf16(const float* __restrict__ s, ushort* __restrict__ d, int n) {
    int i = blockIdx.x * 256 + threadIdx.x;
    if (i < n) d[i] = f2b(s[i]);
}

// ---------------- NCHW -> token-major (R fp32 + A bf16) ----------------
__global__ __launch_bounds__(256)
void k_transpose_in(const float* __restrict__ x, float* __restrict__ R, ushort* __restrict__ A) {
    __shared__ float T[32][33];
    int b = blockIdx.z;
    int hw0 = blockIdx.x * 32, c0 = blockIdx.y * 32;
    int tx = threadIdx.x & 31, ty = threadIdx.x >> 5;
#pragma unroll
    for (int i = 0; i < 4; ++i) {
        int c = ty + i * 8;
        T[c][tx] = x[((size_t)b * 256 + c0 + c) * 4096 + hw0 + tx];
    }
    __syncthreads();
#pragma unroll
    for (int i = 0; i < 4; ++i) {
        int hwl = ty + i * 8;
        float v = T[tx][hwl];
        size_t t = (size_t)b * 4096 + hw0 + hwl;
        R[t * 256 + c0 + tx] = v;
        A[t * 256 + c0 + tx] = f2b(v);
    }
}

// ---------------- NT GEMM: out[m,n] = sum_k A[m,k]*B[n,k]  (bf16 MFMA) ----------------
// EPI 0: bias -> bf16 Co      EPI 1: bias+GELU -> bf16 Co
// EPI 2: bias, R[m,n] += v    EPI 3: bias, Of(NCHW) = R + v   EPI 4: Of(NCHW) += v
template<int EPI>
__global__ __launch_bounds__(256)
void k_gemm_nt(const ushort* __restrict__ A, const ushort* __restrict__ B,
               const float* __restrict__ bias,
               ushort* __restrict__ Co, float* __restrict__ R, float* __restrict__ Of,
               int M, int N, int K, int ldb) {
    __shared__ ushort As[128 * 72];   // +8 bf16 pad -> ~2-way LDS conflicts
    __shared__ ushort Bs[128 * 72];
    int tid = threadIdx.x;
    int lane = tid & 63, w = tid >> 6;
    int row0 = blockIdx.x * 128, col0 = blockIdx.y * 128;
    int wr = (w >> 1) * 64, wc = (w & 1) * 64;
    f32x4 acc[4][4];
#pragma unroll
    for (int mi = 0; mi < 4; ++mi)
#pragma unroll
        for (int ni = 0; ni < 4; ++ni) acc[mi][ni] = (f32x4){0.f, 0.f, 0.f, 0.f};

    int lr = lane & 15, lk = (lane >> 4) << 3;
    for (int k0 = 0; k0 < K; k0 += 64) {
#pragma unroll
        for (int i = 0; i < 4; ++i) {
            int idx = i * 256 + tid;
            int r = idx >> 3, ko = (idx & 7) << 3;
            *(bf16x8*)(As + r * 72 + ko) = *(const bf16x8*)(A + (size_t)(row0 + r) * K + k0 + ko);
            *(bf16x8*)(Bs + r * 72 + ko) = *(const bf16x8*)(B + (size_t)(col0 + r) * ldb + k0 + ko);
        }
        __syncthreads();
#pragma unroll
        for (int kk = 0; kk < 64; kk += 32) {
            bf16x8 af[4], bfm[4];
#pragma unroll
            for (int mi = 0; mi < 4; ++mi) af[mi]  = *(const bf16x8*)(As + (wr + mi * 16 + lr) * 72 + kk + lk);
#pragma unroll
            for (int ni = 0; ni < 4; ++ni) bfm[ni] = *(const bf16x8*)(Bs + (wc + ni * 16 + lr) * 72 + kk + lk);
#pragma unroll
            for (int mi = 0; mi < 4; ++mi)
#pragma unroll
                for (int ni = 0; ni < 4; ++ni)
                    acc[mi][ni] = __builtin_amdgcn_mfma_f32_16x16x32_bf16(af[mi], bfm[ni], acc[mi][ni], 0, 0, 0);
        }
        __syncthreads();
    }

    int lg = lane >> 4;
#pragma unroll
    for (int mi = 0; mi < 4; ++mi)
#pragma unroll
        for (int ni = 0; ni < 4; ++ni)
#pragma unroll
            for (int i = 0; i < 4; ++i) {
                int gr = row0 + wr + mi * 16 + lg * 4 + i;  // token
                int gc = col0 + wc + ni * 16 + lr;          // feature
                float v = acc[mi][ni][i];
                if (EPI != 4) v += bias[gc];
                if (EPI == 0) {
                    Co[(size_t)gr * N + gc] = f2b(v);
                } else if (EPI == 1) {
                    float gl = 0.5f * v * (1.0f + erff(v * 0.70710678118f));
                    Co[(size_t)gr * N + gc] = f2b(gl);
                } else if (EPI == 2) {
                    size_t o = (size_t)gr * 256 + gc;
                    R[o] += v;
                } else if (EPI == 3) {
                    size_t o = (size_t)gr * 256 + gc;
                    float r = R[o] + v;
                    int bb = gr >> 12, hw = gr & 4095;
                    Of[((size_t)bb * 256 + gc) * 4096 + hw] = r;
                } else {
                    int bb = gr >> 12, hw = gr & 4095;
                    Of[((size_t)bb * 256 + gc) * 4096 + hw] += v;
                }
            }
}

// ---------------- depthwise 3x3 + BN2 (token-major bf16) ----------------
__global__ __launch_bounds__(256)
void k_dwconv(const ushort* __restrict__ Hin, const float* __restrict__ wT,
              const float* __restrict__ bf, ushort* __restrict__ Out) {
    int tid = threadIdx.x;
    int p = blockIdx.x * 8 + (tid >> 5);
    int c0 = (tid & 31) << 3;
    int b = p >> 12, hw = p & 4095, h = hw >> 6, ww = hw & 63;
    float acc[8];
    {
        f32x4 b0 = *(const f32x4*)(bf + c0), b1 = *(const f32x4*)(bf + c0 + 4);
        acc[0] = b0.x; acc[1] = b0.y; acc[2] = b0.z; acc[3] = b0.w;
        acc[4] = b1.x; acc[5] = b1.y; acc[6] = b1.z; acc[7] = b1.w;
    }
#pragma unroll
    for (int dy = -1; dy <= 1; ++dy)
#pragma unroll
        for (int dx = -1; dx <= 1; ++dx) {
            int hh = h + dy, w2 = ww + dx;
            if (hh >= 0 && hh < 64 && w2 >= 0 && w2 < 64) {
                int k = (dy + 1) * 3 + (dx + 1);
                bf16x8 v = *(const bf16x8*)(Hin + ((size_t)((b << 12) + (hh << 6) + w2) * 256 + c0));
                f32x4 w0 = *(const f32x4*)(wT + k * 256 + c0);
                f32x4 w1 = *(const f32x4*)(wT + k * 256 + c0 + 4);
                acc[0] += b2f((ushort)v[0]) * w0.x; acc[1] += b2f((ushort)v[1]) * w0.y;
                acc[2] += b2f((ushort)v[2]) * w0.z; acc[3] += b2f((ushort)v[3]) * w0.w;
                acc[4] += b2f((ushort)v[4]) * w1.x; acc[5] += b2f((ushort)v[5]) * w1.y;
                acc[6] += b2f((ushort)v[6]) * w1.z; acc[7] += b2f((ushort)v[7]) * w1.w;
            }
        }
    bf16x8 o;
#pragma unroll
    for (int j = 0; j < 8; ++j) o[j] = (short)f2b(acc[j]);
    *(bf16x8*)(Out + (size_t)p * 256 + c0) = o;
}

// ---------------- LayerNorm over C=256 (one wave per token), fp32 in -> bf16 out ----------------
__global__ __launch_bounds__(256)
void k_ln(const float* __restrict__ R, const float* __restrict__ g,
          const float* __restrict__ be, ushort* __restrict__ O) {
    int lane = threadIdx.x & 63;
    size_t t = (size_t)blockIdx.x * 4 + (threadIdx.x >> 6);
    f32x4 v = *(const f32x4*)(R + t * 256 + lane * 4);
    float s = v.x + v.y + v.z + v.w;
    float q = v.x * v.x + v.y * v.y + v.z * v.z + v.w * v.w;
#pragma unroll
    for (int m = 1; m < 64; m <<= 1) { s += __shfl_xor(s, m, 64); q += __shfl_xor(q, m, 64); }
    float mu = s * (1.f / 256.f);
    float rs = rsqrtf(q * (1.f / 256.f) - mu * mu + EPS);
    int c = lane * 4;
    f32x4 gv = *(const f32x4*)(g + c), bv = *(const f32x4*)(be + c);
    s16x4 o;
    o[0] = (short)f2b((v.x - mu) * rs * gv.x + bv.x);
    o[1] = (short)f2b((v.y - mu) * rs * gv.y + bv.y);
    o[2] = (short)f2b((v.z - mu) * rs * gv.z + bv.z);
    o[3] = (short)f2b((v.w - mu) * rs * gv.w + bv.w);
    *(s16x4*)(O + t * 256 + c) = o;
}

// ---------------- windowed attention: block = (window, 2 heads), wave = 1 head ----------------
__global__ __launch_bounds__(128)
void k_attn(const ushort* __restrict__ QKV, ushort* __restrict__ O) {
    __shared__ float Ks[2][64][64];
    __shared__ float Vs[2][64][64];
    int tid = threadIdx.x;
    int win = blockIdx.x >> 1;
    int hbase = (blockIdx.x & 1) << 1;
    int b = win >> 6, wh = (win >> 3) & 7, wwi = win & 7;
    int rowbase = (b << 12) + (wh << 9) + (wwi << 3);  // b*4096 + wh*8*64 + ww*8

    // stage K,V (2 heads x 64 tok x 64 d) fp32 into LDS
#pragma unroll
    for (int i = 0; i < 8; ++i) {
        int ci = i * 128 + tid;
        int hh = ci >> 9, tok = (ci >> 3) & 63, d0 = (ci & 7) << 3;
        size_t base = ((size_t)(rowbase + ((tok >> 3) << 6) + (tok & 7))) * 768 + (hbase + hh) * 64 + d0;
        bf16x8 kv = *(const bf16x8*)(QKV + base + 256);
        bf16x8 vv = *(const bf16x8*)(QKV + base + 512);
#pragma unroll
        for (int j = 0; j < 8; ++j) {
            Ks[hh][tok][d0 + j] = b2f((ushort)kv[j]);
            Vs[hh][tok][d0 + j] = b2f((ushort)vv[j]);
        }
    }
    __syncthreads();

    int wv = tid >> 6, lane = tid & 63;          // lane = query row
    size_t trow = (size_t)(rowbase + ((lane >> 3) << 6) + (lane & 7));
    size_t qb = trow * 768 + (hbase + wv) * 64;

    float S[64];
#pragma unroll
    for (int c = 0; c < 64; ++c) S[c] = 0.f;

    for (int d0 = 0; d0 < 64; d0 += 8) {
        bf16x8 qv = *(const bf16x8*)(QKV + qb + d0);
        float q8[8];
#pragma unroll
        for (int j = 0; j < 8; ++j) q8[j] = b2f((ushort)qv[j]) * 0.125f;  // fold 1/sqrt(HD)
#pragma unroll
        for (int c = 0; c < 64; ++c) {
            const f32x4* kp = (const f32x4*)&Ks[wv][c][d0];
            f32x4 k0 = kp[0], k1 = kp[1];
            S[c] += q8[0] * k0.x + q8[1] * k0.y + q8[2] * k0.z + q8[3] * k0.w
                  + q8[4] * k1.x + q8[5] * k1.y + q8[6] * k1.z + q8[7] * k1.w;
        }
    }
    float m = S[0];
#pragma unroll
    for (int c = 1; c < 64; ++c) m = fmaxf(m, S[c]);
    float l = 0.f;
#pragma unroll
    for (int c = 0; c < 64; ++c) { float e = __expf(S[c] - m); S[c] = e; l += e; }
    float rl = 1.f / l;

    size_t ob = trow * 256 + (hbase + wv) * 64;
    for (int d0 = 0; d0 < 64; d0 += 8) {
        float o8[8] = {0, 0, 0, 0, 0, 0, 0, 0};
#pragma unroll
        for (int c = 0; c < 64; ++c) {
            const f32x4* vp = (const f32x4*)&Vs[wv][c][d0];
            f32x4 v0 = vp[0], v1 = vp[1];
            o8[0] += S[c] * v0.x; o8[1] += S[c] * v0.y; o8[2] += S[c] * v0.z; o8[3] += S[c] * v0.w;
            o8[4] += S[c] * v1.x; o8[5] += S[c] * v1.y; o8[6] += S[c] * v1.z; o8[7] += S[c] * v1.w;
        }
        bf16x8 ov;
#pragma unroll
        for (int j = 0; j < 8; ++j) ov[j] = (short)f2b(o8[j] * rl);
        *(bf16x8*)(O + ob + d0) = ov;
    }
}

extern "C" void kernel_launch(void* const* d_in, const int* in_sizes, int n_in,
                              void* d_out, int out_size, void* d_ws, size_t ws_size,
                              hipStream_t stream) {
    const float* x       = (const float*)d_in[0];
    const float* conv1_w = (const float*)d_in[1];
    const float* conv1_b = (const float*)d_in[2];
    const float* bn1_g   = (const float*)d_in[3];
    const float* bn1_b   = (const float*)d_in[4];
    const float* bn1_m   = (const float*)d_in[5];
    const float* bn1_v   = (const float*)d_in[6];
    const float* dw_w    = (const float*)d_in[7];
    const float* dw_b    = (const float*)d_in[8];
    const float* bn2_g   = (const float*)d_in[9];
    const float* bn2_b   = (const float*)d_in[10];
    const float* bn2_m   = (const float*)d_in[11];
    const float* bn2_v   = (const float*)d_in[12];
    const float* conv3_w = (const float*)d_in[13];
    const float* conv3_b = (const float*)d_in[14];
    const float* ln1_g   = (const float*)d_in[15];
    const float* ln1_b   = (const float*)d_in[16];
    const float* qkv_w   = (const float*)d_in[17];
    const float* qkv_b   = (const float*)d_in[18];
    const float* proj_w  = (const float*)d_in[19];
    const float* proj_b  = (const float*)d_in[20];
    const float* ln2_g   = (const float*)d_in[21];
    const float* ln2_b   = (const float*)d_in[22];
    const float* mlp_w1  = (const float*)d_in[23];
    const float* mlp_b1  = (const float*)d_in[24];
    const float* mlp_w2  = (const float*)d_in[25];
    const float* mlp_b2  = (const float*)d_in[26];
    float* out = (float*)d_out;

    char* ws = (char*)d_ws;
    float*  R    = (float*)(ws);                          // 64 MB fp32 residual stream [t][256]
    ushort* Abuf = (ushort*)(ws + (64u  << 20));          // 32 MB bf16 [t][256]
    ushort* H1   = (ushort*)(ws + (96u  << 20));          // 32 MB bf16 [t][256]
    ushort* BIG  = (ushort*)(ws + (128u << 20));          // 96 MB bf16: QKV [t][768] / MLP-half [t][512]
    char* wp = ws + (224u << 20);
    ushort* W1f  = (ushort*)wp; wp += 131072;
    float*  b1f  = (float*)wp;  wp += 1024;
    float*  wdwT = (float*)wp;  wp += 9216;
    float*  bdw  = (float*)wp;  wp += 1024;
    ushort* W3   = (ushort*)wp; wp += 131072;
    ushort* Wqkv = (ushort*)wp; wp += 393216;
    ushort* Wproj= (ushort*)wp; wp += 131072;
    ushort* Wm1  = (ushort*)wp; wp += 524288;
    ushort* Wm2  = (ushort*)wp; wp += 524288;

    // weight prep (tiny)
    k_fold_conv1<<<256, 256, 0, stream>>>(conv1_w, conv1_b, bn1_g, bn1_b, bn1_m, bn1_v, W1f, b1f);
    k_fold_dw<<<9, 256, 0, stream>>>(dw_w, dw_b, bn2_g, bn2_b, bn2_m, bn2_v, wdwT, bdw);
    k_cvt_bf16<<<256, 256, 0, stream>>>(conv3_w, W3, 65536);
    k_cvt_bf16<<<768, 256, 0, stream>>>(qkv_w, Wqkv, 196608);
    k_cvt_bf16<<<256, 256, 0, stream>>>(proj_w, Wproj, 65536);
    k_cvt_bf16<<<1024, 256, 0, stream>>>(mlp_w1, Wm1, 262144);
    k_cvt_bf16<<<1024, 256, 0, stream>>>(mlp_w2, Wm2, 262144);

    // NCHW -> token-major
    k_transpose_in<<<dim3(128, 8, 16), 256, 0, stream>>>(x, R, Abuf);

    // conv path
    k_gemm_nt<0><<<dim3(512, 2), 256, 0, stream>>>(Abuf, W1f, b1f, H1, nullptr, nullptr, 65536, 256, 256, 256);
    k_dwconv<<<8192, 256, 0, stream>>>(H1, wdwT, bdw, Abuf);
    k_gemm_nt<2><<<dim3(512, 2), 256, 0, stream>>>(Abuf, W3, conv3_b, nullptr, R, nullptr, 65536, 256, 256, 256);

    // attention
    k_ln<<<16384, 256, 0, stream>>>(R, ln1_g, ln1_b, Abuf);
    k_gemm_nt<0><<<dim3(512, 6), 256, 0, stream>>>(Abuf, Wqkv, qkv_b, BIG, nullptr, nullptr, 65536, 768, 256, 256);
    k_attn<<<2048, 128, 0, stream>>>(BIG, H1);
    k_gemm_nt<2><<<dim3(512, 2), 256, 0, stream>>>(H1, Wproj, proj_b, nullptr, R, nullptr, 65536, 256, 256, 256);

    // FFN (hidden split in two 512-wide halves to bound workspace)
    k_ln<<<16384, 256, 0, stream>>>(R, ln2_g, ln2_b, Abuf);
    k_gemm_nt<1><<<dim3(512, 4), 256, 0, stream>>>(Abuf, Wm1, mlp_b1, BIG, nullptr, nullptr, 65536, 512, 256, 256);
    k_gemm_nt<3><<<dim3(512, 2), 256, 0, stream>>>(BIG, Wm2, mlp_b2, nullptr, R, out, 65536, 256, 512, 1024);
    k_gemm_nt<1><<<dim3(512, 4), 256, 0, stream>>>(Abuf, Wm1 + 512 * 256, mlp_b1 + 512, BIG, nullptr, nullptr, 65536, 512, 256, 256);
    k_gemm_nt<4><<<dim3(512, 2), 256, 0, stream>>>(BIG, Wm2 + 512, nullptr, nullptr, nullptr, out, 65536, 256, 512, 1024);
}

// Round 2
// 559.762 us; speedup vs baseline: 1.1692x; 1.1692x over previous
//
#include <hip/hip_runtime.h>
#include <hip/hip_bf16.h>

#define EPS 1e-5f

typedef __attribute__((ext_vector_type(8))) short bf16x8;
typedef __attribute__((ext_vector_type(4))) float f32x4;
typedef __attribute__((ext_vector_type(4))) short s16x4;

__device__ __forceinline__ float b2f(ushort u) {
    union { uint i; float f; } v; v.i = ((uint)u) << 16; return v.f;
}
__device__ __forceinline__ ushort f2b(float f) {  // RNE f32->bf16
    uint x = __float_as_uint(f);
    return (ushort)((x + 0x7fffu + ((x >> 16) & 1u)) >> 16);
}

#define ASYNC16(dst_lds, src_g) \
    __builtin_amdgcn_global_load_lds((const __attribute__((address_space(1))) void*)(src_g), \
                                     (__attribute__((address_space(3))) void*)(dst_lds), 16, 0, 0)

// ---------------- weight prep ----------------
__global__ void k_fold_conv1(const float* __restrict__ w, const float* __restrict__ cb,
                             const float* __restrict__ g, const float* __restrict__ be,
                             const float* __restrict__ mn, const float* __restrict__ vr,
                             ushort* __restrict__ Wf, float* __restrict__ bf) {
    int i = blockIdx.x * 256 + threadIdx.x;   // 65536 = 256x256
    int o = i >> 8;
    float inv = g[o] * rsqrtf(vr[o] + EPS);
    Wf[i] = f2b(w[i] * inv);
    if ((i & 255) == 0) bf[o] = cb[o] * inv + be[o] - mn[o] * inv;
}

__global__ void k_fold_dw(const float* __restrict__ w, const float* __restrict__ cb,
                          const float* __restrict__ g, const float* __restrict__ be,
                          const float* __restrict__ mn, const float* __restrict__ vr,
                          float* __restrict__ wT, float* __restrict__ bf) {
    int i = blockIdx.x * 256 + threadIdx.x;
    if (i < 2304) {                           // 256 ch x 9 taps
        int c = i / 9, k = i % 9;
        float inv = g[c] * rsqrtf(vr[c] + EPS);
        wT[k * 256 + c] = w[i] * inv;         // transposed [9][256] for vector reads
    }
    if (i < 256) {
        float inv = g[i] * rsqrtf(vr[i] + EPS);
        bf[i] = cb[i] * inv + be[i] - mn[i] * inv;
    }
}

__global__ void k_cvt_bf16(const float* __restrict__ s, ushort* __restrict__ d, int n) {
    int i = blockIdx.x * 256 + threadIdx.x;
    if (i < n) d[i] = f2b(s[i]);
}

// ---------------- NCHW -> token-major (R fp32 + A bf16) ----------------
__global__ __launch_bounds__(256)
void k_transpose_in(const float* __restrict__ x, float* __restrict__ R, ushort* __restrict__ A) {
    __shared__ float T[32][33];
    int b = blockIdx.z;
    int hw0 = blockIdx.x * 32, c0 = blockIdx.y * 32;
    int tx = threadIdx.x & 31, ty = threadIdx.x >> 5;
#pragma unroll
    for (int i = 0; i < 4; ++i) {
        int c = ty + i * 8;
        T[c][tx] = x[((size_t)b * 256 + c0 + c) * 4096 + hw0 + tx];
    }
    __syncthreads();
#pragma unroll
    for (int i = 0; i < 4; ++i) {
        int hwl = ty + i * 8;
        float v = T[tx][hwl];
        size_t t = (size_t)b * 4096 + hw0 + hwl;
        R[t * 256 + c0 + tx] = v;
        A[t * 256 + c0 + tx] = f2b(v);
    }
}

// ---------------- NT GEMM: out[m,n] = sum_k A[m,k]*B[n,k]  (bf16 MFMA, m97-style DMA staging)
// EPI 0: bias -> bf16 Co      EPI 1: bias+GELU -> bf16 Co
// EPI 2: bias, R[m,n] += v    EPI 3: bias, Of(NCHW) = R + v   EPI 4: Of(NCHW) += v
template<int EPI>
__global__ __launch_bounds__(256)
void k_gemm_nt(const ushort* __restrict__ A, const ushort* __restrict__ B,
               const float* __restrict__ bias,
               ushort* __restrict__ Co, float* __restrict__ R, float* __restrict__ Of,
               int M, int N, int K, int ldb) {
    __shared__ ushort As[128 * 64];   // linear: global_load_lds dest must be unpadded
    __shared__ ushort Bs[128 * 64];
    int tid = threadIdx.x;
    int lane = tid & 63, w = tid >> 6;
    int row0 = blockIdx.x * 128, col0 = blockIdx.y * 128;
    int wr = (w >> 1) * 64, wc = (w & 1) * 64;
    f32x4 acc[4][4];
#pragma unroll
    for (int mi = 0; mi < 4; ++mi)
#pragma unroll
        for (int ni = 0; ni < 4; ++ni) acc[mi][ni] = (f32x4){0.f, 0.f, 0.f, 0.f};

    int lr = lane & 15, lk = (lane >> 4) << 3;
    int rin = lane >> 3, cin = (lane & 7) << 3;   // staging lane layout
    for (int k0 = 0; k0 < K; k0 += 64) {
#pragma unroll
        for (int i = 0; i < 4; ++i) {
            int c = (w << 2) + i;                 // chunk 0..15 (8 rows each)
            int r = (c << 3) + rin;
            ASYNC16(As + (c << 9), A + (size_t)(row0 + r) * K + k0 + cin);
            ASYNC16(Bs + (c << 9), B + (size_t)(col0 + r) * ldb + k0 + cin);
        }
        __syncthreads();                          // drains vmcnt -> LDS valid
#pragma unroll
        for (int kk = 0; kk < 64; kk += 32) {
            bf16x8 af[4], bfm[4];
#pragma unroll
            for (int mi = 0; mi < 4; ++mi) af[mi]  = *(const bf16x8*)(As + (wr + mi * 16 + lr) * 64 + kk + lk);
#pragma unroll
            for (int ni = 0; ni < 4; ++ni) bfm[ni] = *(const bf16x8*)(Bs + (wc + ni * 16 + lr) * 64 + kk + lk);
#pragma unroll
            for (int mi = 0; mi < 4; ++mi)
#pragma unroll
                for (int ni = 0; ni < 4; ++ni)
                    acc[mi][ni] = __builtin_amdgcn_mfma_f32_16x16x32_bf16(af[mi], bfm[ni], acc[mi][ni], 0, 0, 0);
        }
        __syncthreads();
    }

    int lg = lane >> 4;
#pragma unroll
    for (int mi = 0; mi < 4; ++mi)
#pragma unroll
        for (int ni = 0; ni < 4; ++ni)
#pragma unroll
            for (int i = 0; i < 4; ++i) {
                int gr = row0 + wr + mi * 16 + lg * 4 + i;  // token
                int gc = col0 + wc + ni * 16 + lr;          // feature
                float v = acc[mi][ni][i];
                if (EPI != 4) v += bias[gc];
                if (EPI == 0) {
                    Co[(size_t)gr * N + gc] = f2b(v);
                } else if (EPI == 1) {
                    float gl = 0.5f * v * (1.0f + erff(v * 0.70710678118f));
                    Co[(size_t)gr * N + gc] = f2b(gl);
                } else if (EPI == 2) {
                    size_t o = (size_t)gr * 256 + gc;
                    R[o] += v;
                } else if (EPI == 3) {
                    size_t o = (size_t)gr * 256 + gc;
                    float r = R[o] + v;
                    int bb = gr >> 12, hw = gr & 4095;
                    Of[((size_t)bb * 256 + gc) * 4096 + hw] = r;
                } else {
                    int bb = gr >> 12, hw = gr & 4095;
                    Of[((size_t)bb * 256 + gc) * 4096 + hw] += v;
                }
            }
}

// ---------------- depthwise 3x3 + BN2, 4 pixels/thread (token-major bf16) ----------------
__global__ __launch_bounds__(256)
void k_dwconv(const ushort* __restrict__ Hin, const float* __restrict__ wT,
              const float* __restrict__ bf, ushort* __restrict__ Out) {
    int tid = threadIdx.x;
    int pg = blockIdx.x * 8 + (tid >> 5);
    int c0 = (tid & 31) << 3;
    int p0 = pg << 2;                  // 4 consecutive pixels, same row
    int b12 = p0 & ~4095;
    int hw = p0 & 4095, h0 = hw >> 6, w0 = hw & 63;

    float wreg[9][8];
#pragma unroll
    for (int k = 0; k < 9; ++k) {
        f32x4 a = *(const f32x4*)(wT + k * 256 + c0);
        f32x4 bq = *(const f32x4*)(wT + k * 256 + c0 + 4);
        wreg[k][0] = a.x; wreg[k][1] = a.y; wreg[k][2] = a.z; wreg[k][3] = a.w;
        wreg[k][4] = bq.x; wreg[k][5] = bq.y; wreg[k][6] = bq.z; wreg[k][7] = bq.w;
    }
    float acc[4][8];
    {
        f32x4 b0 = *(const f32x4*)(bf + c0), b1 = *(const f32x4*)(bf + c0 + 4);
#pragma unroll
        for (int px = 0; px < 4; ++px) {
            acc[px][0] = b0.x; acc[px][1] = b0.y; acc[px][2] = b0.z; acc[px][3] = b0.w;
            acc[px][4] = b1.x; acc[px][5] = b1.y; acc[px][6] = b1.z; acc[px][7] = b1.w;
        }
    }
#pragma unroll
    for (int dy = -1; dy <= 1; ++dy) {
        int hy = h0 + dy;
        if ((unsigned)hy >= 64u) continue;
        const ushort* rp = Hin + (((size_t)(b12 + (hy << 6))) << 8) + c0;
#pragma unroll
        for (int dx = -1; dx <= 4; ++dx) {
            int col = w0 + dx;
            if ((unsigned)col >= 64u) continue;
            bf16x8 v = *(const bf16x8*)(rp + ((size_t)col << 8));
            float vf[8];
#pragma unroll
            for (int j = 0; j < 8; ++j) vf[j] = b2f((ushort)v[j]);
#pragma unroll
            for (int px = 0; px < 4; ++px) {
                int kx = dx - px + 1;
                if (kx < 0 || kx > 2) continue;
                int k = (dy + 1) * 3 + kx;
#pragma unroll
                for (int j = 0; j < 8; ++j) acc[px][j] += vf[j] * wreg[k][j];
            }
        }
    }
#pragma unroll
    for (int px = 0; px < 4; ++px) {
        bf16x8 o;
#pragma unroll
        for (int j = 0; j < 8; ++j) o[j] = (short)f2b(acc[px][j]);
        *(bf16x8*)(Out + (size_t)(p0 + px) * 256 + c0) = o;
    }
}

// ---------------- LayerNorm over C=256 (one wave per token), fp32 in -> bf16 out ----------------
__global__ __launch_bounds__(256)
void k_ln(const float* __restrict__ R, const float* __restrict__ g,
          const float* __restrict__ be, ushort* __restrict__ O) {
    int lane = threadIdx.x & 63;
    size_t t = (size_t)blockIdx.x * 4 + (threadIdx.x >> 6);
    f32x4 v = *(const f32x4*)(R + t * 256 + lane * 4);
    float s = v.x + v.y + v.z + v.w;
    float q = v.x * v.x + v.y * v.y + v.z * v.z + v.w * v.w;
#pragma unroll
    for (int m = 1; m < 64; m <<= 1) { s += __shfl_xor(s, m, 64); q += __shfl_xor(q, m, 64); }
    float mu = s * (1.f / 256.f);
    float rs = rsqrtf(q * (1.f / 256.f) - mu * mu + EPS);
    int c = lane * 4;
    f32x4 gv = *(const f32x4*)(g + c), bv = *(const f32x4*)(be + c);
    s16x4 o;
    o[0] = (short)f2b((v.x - mu) * rs * gv.x + bv.x);
    o[1] = (short)f2b((v.y - mu) * rs * gv.y + bv.y);
    o[2] = (short)f2b((v.z - mu) * rs * gv.z + bv.z);
    o[3] = (short)f2b((v.w - mu) * rs * gv.w + bv.w);
    *(s16x4*)(O + t * 256 + c) = o;
}

// ---------------- windowed attention, MFMA version ----------------
// block = 1 window (256 thr, 4 waves); wave = 1 head. S^T = mfma(K,Q); in-reg softmax;
// P -> per-wave LDS (A-operand relayout); V staged through SAME LDS (time-shared).
__global__ __launch_bounds__(256)
void k_attn(const ushort* __restrict__ QKV, ushort* __restrict__ O) {
    __shared__ ushort SH[4][64 * 68];             // 34816 B total
    const int tid = threadIdx.x;
    const int w = tid >> 6, lane = tid & 63;
    const int lr = lane & 15, lg = lane >> 4;
    const int win = blockIdx.x;
    const int b = win >> 6, wh = (win >> 3) & 7, ww = win & 7;
    const int rowbase = (b << 12) + (wh << 9) + (ww << 3);
    const int h = w;

#define TROW(tok) (rowbase + (((tok) >> 3) << 6) + ((tok) & 7))

    bf16x8 qB[4][2], kA[4][2], vR[8];
#pragma unroll
    for (int f = 0; f < 4; ++f) {
        size_t t = (size_t)TROW(f * 16 + lr);
        const ushort* qp = QKV + t * 768 + h * 64 + lg * 8;
#pragma unroll
        for (int ks = 0; ks < 2; ++ks) {
            qB[f][ks] = *(const bf16x8*)(qp + ks * 32);        // Q[q][d]  (B-operand)
            kA[f][ks] = *(const bf16x8*)(qp + 256 + ks * 32);  // K[k][d]  (A-operand)
        }
    }
    {   // V row loads issued early (hide under QK^T)
        size_t t = (size_t)TROW(lane);
        const ushort* vp = QKV + t * 768 + 512 + h * 64;
#pragma unroll
        for (int i = 0; i < 8; ++i) vR[i] = *(const bf16x8*)(vp + i * 8);
    }

    // S^T[key][query]: D col = query = lr, row = key = lg*4+i (+16*kf)
    f32x4 st[4][4];
#pragma unroll
    for (int kf = 0; kf < 4; ++kf)
#pragma unroll
        for (int qf = 0; qf < 4; ++qf) st[kf][qf] = (f32x4){0.f, 0.f, 0.f, 0.f};
#pragma unroll
    for (int ks = 0; ks < 2; ++ks)
#pragma unroll
        for (int kf = 0; kf < 4; ++kf)
#pragma unroll
            for (int qf = 0; qf < 4; ++qf)
                st[kf][qf] = __builtin_amdgcn_mfma_f32_16x16x32_bf16(kA[kf][ks], qB[qf][ks], st[kf][qf], 0, 0, 0);

    // softmax over keys (16 local values + 4-lane-group shfl reduce), write P to LDS
    ushort* P = &SH[w][0];
#pragma unroll
    for (int qf = 0; qf < 4; ++qf) {
        float m = -1e30f;
#pragma unroll
        for (int kf = 0; kf < 4; ++kf)
#pragma unroll
            for (int i = 0; i < 4; ++i) m = fmaxf(m, st[kf][qf][i]);
        m = fmaxf(m, __shfl_xor(m, 16, 64));
        m = fmaxf(m, __shfl_xor(m, 32, 64));
        m *= 0.125f;
        float sum = 0.f;
#pragma unroll
        for (int kf = 0; kf < 4; ++kf) {
            f32x4 e;
#pragma unroll
            for (int i = 0; i < 4; ++i) { e[i] = __expf(st[kf][qf][i] * 0.125f - m); sum += e[i]; }
            st[kf][qf] = e;
        }
        sum += __shfl_xor(sum, 16, 64);
        sum += __shfl_xor(sum, 32, 64);
        float rl = 1.f / sum;
#pragma unroll
        for (int kf = 0; kf < 4; ++kf) {
            s16x4 pk;
#pragma unroll
            for (int i = 0; i < 4; ++i) pk[i] = (short)f2b(st[kf][qf][i] * rl);
            *(s16x4*)(P + (qf * 16 + lr) * 68 + kf * 16 + lg * 4) = pk;  // P[q][key], ld=68
        }
    }
    // read P back as A-operand fragments: lane holds P[q=lr+16mf][key=lg*8+j+32ks]
    bf16x8 pA[4][2];
#pragma unroll
    for (int mf = 0; mf < 4; ++mf)
#pragma unroll
        for (int ks = 0; ks < 2; ++ks) {
            union { bf16x8 v8; s16x4 v4[2]; } u;
            const ushort* p = P + (mf * 16 + lr) * 68 + ks * 32 + lg * 8;
            u.v4[0] = *(const s16x4*)(p);
            u.v4[1] = *(const s16x4*)(p + 4);
            pA[mf][ks] = u.v8;
        }
    asm volatile("s_waitcnt lgkmcnt(0)" ::: "memory");   // P reads done before V overwrites
    __builtin_amdgcn_sched_barrier(0);
    // stage V into same buffer: V[key][d], ld=68
#pragma unroll
    for (int i = 0; i < 8; ++i) {
        union { bf16x8 v8; s16x4 v4[2]; } u; u.v8 = vR[i];
        *(s16x4*)(P + lane * 68 + i * 8) = u.v4[0];
        *(s16x4*)(P + lane * 68 + i * 8 + 4) = u.v4[1];
    }
    asm volatile("s_waitcnt lgkmcnt(0)" ::: "memory");
    __builtin_amdgcn_sched_barrier(0);
    // V^T gather (B-operand): lane holds V[key=lg*8+j+32ks][d=lr+16nf]
    bf16x8 vB[4][2];
#pragma unroll
    for (int nf = 0; nf < 4; ++nf)
#pragma unroll
        for (int ks = 0; ks < 2; ++ks) {
            bf16x8 vb;
#pragma unroll
            for (int j = 0; j < 8; ++j)
                vb[j] = (short)P[(ks * 32 + lg * 8 + j) * 68 + nf * 16 + lr];
            vB[nf][ks] = vb;
        }
    // O[q][d] = P·V : D row = q = lg*4+i (+16mf), col = d = lr (+16nf)
    f32x4 o[4][4];
#pragma unroll
    for (int mf = 0; mf < 4; ++mf)
#pragma unroll
        for (int nf = 0; nf < 4; ++nf) o[mf][nf] = (f32x4){0.f, 0.f, 0.f, 0.f};
#pragma unroll
    for (int ks = 0; ks < 2; ++ks)
#pragma unroll
        for (int mf = 0; mf < 4; ++mf)
#pragma unroll
            for (int nf = 0; nf < 4; ++nf)
                o[mf][nf] = __builtin_amdgcn_mfma_f32_16x16x32_bf16(pA[mf][ks], vB[nf][ks], o[mf][nf], 0, 0, 0);
#pragma unroll
    for (int mf = 0; mf < 4; ++mf)
#pragma unroll
        for (int nf = 0; nf < 4; ++nf)
#pragma unroll
            for (int i = 0; i < 4; ++i) {
                int q = mf * 16 + lg * 4 + i;
                int d = nf * 16 + lr;
                O[(size_t)TROW(q) * 256 + h * 64 + d] = f2b(o[mf][nf][i]);
            }
#undef TROW
}

extern "C" void kernel_launch(void* const* d_in, const int* in_sizes, int n_in,
                              void* d_out, int out_size, void* d_ws, size_t ws_size,
                              hipStream_t stream) {
    const float* x       = (const float*)d_in[0];
    const float* conv1_w = (const float*)d_in[1];
    const float* conv1_b = (const float*)d_in[2];
    const float* bn1_g   = (const float*)d_in[3];
    const float* bn1_b   = (const float*)d_in[4];
    const float* bn1_m   = (const float*)d_in[5];
    const float* bn1_v   = (const float*)d_in[6];
    const float* dw_w    = (const float*)d_in[7];
    const float* dw_b    = (const float*)d_in[8];
    const float* bn2_g   = (const float*)d_in[9];
    const float* bn2_b   = (const float*)d_in[10];
    const float* bn2_m   = (const float*)d_in[11];
    const float* bn2_v   = (const float*)d_in[12];
    const float* conv3_w = (const float*)d_in[13];
    const float* conv3_b = (const float*)d_in[14];
    const float* ln1_g   = (const float*)d_in[15];
    const float* ln1_b   = (const float*)d_in[16];
    const float* qkv_w   = (const float*)d_in[17];
    const float* qkv_b   = (const float*)d_in[18];
    const float* proj_w  = (const float*)d_in[19];
    const float* proj_b  = (const float*)d_in[20];
    const float* ln2_g   = (const float*)d_in[21];
    const float* ln2_b   = (const float*)d_in[22];
    const float* mlp_w1  = (const float*)d_in[23];
    const float* mlp_b1  = (const float*)d_in[24];
    const float* mlp_w2  = (const float*)d_in[25];
    const float* mlp_b2  = (const float*)d_in[26];
    float* out = (float*)d_out;

    char* ws = (char*)d_ws;
    float*  R    = (float*)(ws);                          // 64 MB fp32 residual stream [t][256]
    ushort* Abuf = (ushort*)(ws + (64u  << 20));          // 32 MB bf16 [t][256]
    ushort* H1   = (ushort*)(ws + (96u  << 20));          // 32 MB bf16 [t][256]
    ushort* BIG  = (ushort*)(ws + (128u << 20));          // 96 MB bf16: QKV [t][768] / MLP-half [t][512]
    char* wp = ws + (224u << 20);
    ushort* W1f  = (ushort*)wp; wp += 131072;
    float*  b1f  = (float*)wp;  wp += 1024;
    float*  wdwT = (float*)wp;  wp += 9216;
    float*  bdw  = (float*)wp;  wp += 1024;
    ushort* W3   = (ushort*)wp; wp += 131072;
    ushort* Wqkv = (ushort*)wp; wp += 393216;
    ushort* Wproj= (ushort*)wp; wp += 131072;
    ushort* Wm1  = (ushort*)wp; wp += 524288;
    ushort* Wm2  = (ushort*)wp; wp += 524288;

    // weight prep (tiny)
    k_fold_conv1<<<256, 256, 0, stream>>>(conv1_w, conv1_b, bn1_g, bn1_b, bn1_m, bn1_v, W1f, b1f);
    k_fold_dw<<<9, 256, 0, stream>>>(dw_w, dw_b, bn2_g, bn2_b, bn2_m, bn2_v, wdwT, bdw);
    k_cvt_bf16<<<256, 256, 0, stream>>>(conv3_w, W3, 65536);
    k_cvt_bf16<<<768, 256, 0, stream>>>(qkv_w, Wqkv, 196608);
    k_cvt_bf16<<<256, 256, 0, stream>>>(proj_w, Wproj, 65536);
    k_cvt_bf16<<<1024, 256, 0, stream>>>(mlp_w1, Wm1, 262144);
    k_cvt_bf16<<<1024, 256, 0, stream>>>(mlp_w2, Wm2, 262144);

    // NCHW -> token-major
    k_transpose_in<<<dim3(128, 8, 16), 256, 0, stream>>>(x, R, Abuf);

    // conv path
    k_gemm_nt<0><<<dim3(512, 2), 256, 0, stream>>>(Abuf, W1f, b1f, H1, nullptr, nullptr, 65536, 256, 256, 256);
    k_dwconv<<<2048, 256, 0, stream>>>(H1, wdwT, bdw, Abuf);
    k_gemm_nt<2><<<dim3(512, 2), 256, 0, stream>>>(Abuf, W3, conv3_b, nullptr, R, nullptr, 65536, 256, 256, 256);

    // attention
    k_ln<<<16384, 256, 0, stream>>>(R, ln1_g, ln1_b, Abuf);
    k_gemm_nt<0><<<dim3(512, 6), 256, 0, stream>>>(Abuf, Wqkv, qkv_b, BIG, nullptr, nullptr, 65536, 768, 256, 256);
    k_attn<<<1024, 256, 0, stream>>>(BIG, H1);
    k_gemm_nt<2><<<dim3(512, 2), 256, 0, stream>>>(H1, Wproj, proj_b, nullptr, R, nullptr, 65536, 256, 256, 256);

    // FFN (hidden split in two 512-wide halves to bound workspace)
    k_ln<<<16384, 256, 0, stream>>>(R, ln2_g, ln2_b, Abuf);
    k_gemm_nt<1><<<dim3(512, 4), 256, 0, stream>>>(Abuf, Wm1, mlp_b1, BIG, nullptr, nullptr, 65536, 512, 256, 256);
    k_gemm_nt<3><<<dim3(512, 2), 256, 0, stream>>>(BIG, Wm2, mlp_b2, nullptr, R, out, 65536, 256, 512, 1024);
    k_gemm_nt<1><<<dim3(512, 4), 256, 0, stream>>>(Abuf, Wm1 + 512 * 256, mlp_b1 + 512, BIG, nullptr, nullptr, 65536, 512, 256, 256);
    k_gemm_nt<4><<<dim3(512, 2), 256, 0, stream>>>(BIG, Wm2 + 512, nullptr, nullptr, nullptr, out, 65536, 256, 512, 1024);
}

// Round 3
// 430.873 us; speedup vs baseline: 1.5190x; 1.2991x over previous
//
#include <hip/hip_runtime.h>
#include <hip/hip_bf16.h>

#define EPS 1e-5f

typedef __attribute__((ext_vector_type(8))) short bf16x8;
typedef __attribute__((ext_vector_type(4))) float f32x4;
typedef __attribute__((ext_vector_type(4))) short s16x4;

__device__ __forceinline__ float b2f(ushort u) {
    union { uint i; float f; } v; v.i = ((uint)u) << 16; return v.f;
}
__device__ __forceinline__ ushort f2b(float f) {  // RNE f32->bf16
    uint x = __float_as_uint(f);
    return (ushort)((x + 0x7fffu + ((x >> 16) & 1u)) >> 16);
}

#define ASYNC16(dst_lds, src_g) \
    __builtin_amdgcn_global_load_lds((const __attribute__((address_space(1))) void*)(src_g), \
                                     (__attribute__((address_space(3))) void*)(dst_lds), 16, 0, 0)

// ---------------- weight prep ----------------
__global__ void k_fold_conv1(const float* __restrict__ w, const float* __restrict__ cb,
                             const float* __restrict__ g, const float* __restrict__ be,
                             const float* __restrict__ mn, const float* __restrict__ vr,
                             ushort* __restrict__ Wf, float* __restrict__ bf) {
    int i = blockIdx.x * 256 + threadIdx.x;   // 65536 = 256x256
    int o = i >> 8;
    float inv = g[o] * rsqrtf(vr[o] + EPS);
    Wf[i] = f2b(w[i] * inv);
    if ((i & 255) == 0) bf[o] = cb[o] * inv + be[o] - mn[o] * inv;
}

__global__ void k_fold_dw(const float* __restrict__ w, const float* __restrict__ cb,
                          const float* __restrict__ g, const float* __restrict__ be,
                          const float* __restrict__ mn, const float* __restrict__ vr,
                          float* __restrict__ wT, float* __restrict__ bf) {
    int i = blockIdx.x * 256 + threadIdx.x;
    if (i < 2304) {                           // 256 ch x 9 taps
        int c = i / 9, k = i % 9;
        float inv = g[c] * rsqrtf(vr[c] + EPS);
        wT[k * 256 + c] = w[i] * inv;         // transposed [9][256] for vector reads
    }
    if (i < 256) {
        float inv = g[i] * rsqrtf(vr[i] + EPS);
        bf[i] = cb[i] * inv + be[i] - mn[i] * inv;
    }
}

__global__ void k_cvt_bf16(const float* __restrict__ s, ushort* __restrict__ d, int n) {
    int i = blockIdx.x * 256 + threadIdx.x;
    if (i < n) d[i] = f2b(s[i]);
}

// ---------------- NCHW -> token-major (R fp32 + A bf16) ----------------
__global__ __launch_bounds__(256)
void k_transpose_in(const float* __restrict__ x, float* __restrict__ R, ushort* __restrict__ A) {
    __shared__ float T[32][33];
    int b = blockIdx.z;
    int hw0 = blockIdx.x * 32, c0 = blockIdx.y * 32;
    int tx = threadIdx.x & 31, ty = threadIdx.x >> 5;
#pragma unroll
    for (int i = 0; i < 4; ++i) {
        int c = ty + i * 8;
        T[c][tx] = x[((size_t)b * 256 + c0 + c) * 4096 + hw0 + tx];
    }
    __syncthreads();
#pragma unroll
    for (int i = 0; i < 4; ++i) {
        int hwl = ty + i * 8;
        float v = T[tx][hwl];
        size_t t = (size_t)b * 4096 + hw0 + hwl;
        R[t * 256 + c0 + tx] = v;
        A[t * 256 + c0 + tx] = f2b(v);
    }
}

// ---------------- NT GEMM: out[m,n] = sum_k A[m,k]*B[n,k]
// 2-phase double-buffered global_load_lds staging + T2 both-sides XOR swizzle.
// EPI 0: bias -> bf16 Co      EPI 2: bias, R[m,n] += v
template<int EPI>
__global__ __launch_bounds__(256)
void k_gemm_nt(const ushort* __restrict__ A, const ushort* __restrict__ B,
               const float* __restrict__ bias,
               ushort* __restrict__ Co, float* __restrict__ R,
               int M, int N, int K, int ldb) {
    __shared__ ushort As[2][128 * 64];
    __shared__ ushort Bs[2][128 * 64];
    int tid = threadIdx.x;
    int lane = tid & 63, w = tid >> 6;
    int row0 = blockIdx.x * 128, col0 = blockIdx.y * 128;
    int wr = (w >> 1) * 64, wc = (w & 1) * 64;
    f32x4 acc[4][4];
#pragma unroll
    for (int mi = 0; mi < 4; ++mi)
#pragma unroll
        for (int ni = 0; ni < 4; ++ni) acc[mi][ni] = (f32x4){0.f, 0.f, 0.f, 0.f};

    int lr = lane & 15, lk = (lane >> 4) << 3;
    int rin = lane >> 3;                                   // row within 8-row chunk
    int cin_sw = (((lane & 7) ^ (rin & 7)) << 3);          // swizzled source col (ushorts)
    int rxor = (lr & 7) << 3;                              // read-side XOR (row&7 == lr&7)

#define GSTAGE(buf, k0)                                                                   \
    _Pragma("unroll")                                                                     \
    for (int i = 0; i < 4; ++i) {                                                         \
        int c = (w << 2) + i;                                                             \
        int r = (c << 3) + rin;                                                           \
        ASYNC16(As[buf] + (c << 9), A + (size_t)(row0 + r) * K + (k0) + cin_sw);          \
        ASYNC16(Bs[buf] + (c << 9), B + (size_t)(col0 + r) * ldb + (k0) + cin_sw);        \
    }

    GSTAGE(0, 0);
    __syncthreads();                                       // implicit vmcnt(0) drain
    int nt = K >> 6;
    for (int t = 0; t < nt; ++t) {
        int cur = t & 1;
        if (t + 1 < nt) { GSTAGE(cur ^ 1, (t + 1) << 6); } // prefetch next K-tile
#pragma unroll
        for (int kk = 0; kk < 64; kk += 32) {
            bf16x8 af[4], bfm[4];
#pragma unroll
            for (int mi = 0; mi < 4; ++mi)
                af[mi]  = *(const bf16x8*)(As[cur] + (wr + mi * 16 + lr) * 64 + ((kk + lk) ^ rxor));
#pragma unroll
            for (int ni = 0; ni < 4; ++ni)
                bfm[ni] = *(const bf16x8*)(Bs[cur] + (wc + ni * 16 + lr) * 64 + ((kk + lk) ^ rxor));
#pragma unroll
            for (int mi = 0; mi < 4; ++mi)
#pragma unroll
                for (int ni = 0; ni < 4; ++ni)
                    acc[mi][ni] = __builtin_amdgcn_mfma_f32_16x16x32_bf16(af[mi], bfm[ni], acc[mi][ni], 0, 0, 0);
        }
        __syncthreads();                                   // vmcnt(0)+barrier: next buf ready
    }
#undef GSTAGE

    int lg = lane >> 4;
#pragma unroll
    for (int mi = 0; mi < 4; ++mi)
#pragma unroll
        for (int ni = 0; ni < 4; ++ni)
#pragma unroll
            for (int i = 0; i < 4; ++i) {
                int gr = row0 + wr + mi * 16 + lg * 4 + i;  // token
                int gc = col0 + wc + ni * 16 + lr;          // feature
                float v = acc[mi][ni][i] + bias[gc];
                if (EPI == 0) {
                    Co[(size_t)gr * N + gc] = f2b(v);
                } else {
                    R[(size_t)gr * 256 + gc] += v;
                }
            }
}

// ---------------- fused MLP: out(NCHW) = R + (GELU(A@W1^T+b1))@W2^T + b2
// block = 64 tokens, 8 waves. Hidden processed in 8 chunks of 128; P bounced
// through swizzled LDS; out accumulated in registers. Weights read from L2.
__global__ __launch_bounds__(512)
void k_mlp(const ushort* __restrict__ Aln, const ushort* __restrict__ W1,
           const float* __restrict__ b1, const ushort* __restrict__ W2,
           const float* __restrict__ b2, const float* __restrict__ R,
           float* __restrict__ out) {
    __shared__ ushort As[64 * 256];   // 32 KB (swizzled content)
    __shared__ ushort Ps[64 * 128];   // 16 KB (swizzled content)
    const int tid = threadIdx.x, lane = tid & 63, w = tid >> 6;  // 8 waves
    const int lr = lane & 15, lg = lane >> 4;
    const int row0 = blockIdx.x << 6;
    const int rxor = (lr & 7) << 3;

    // stage A: 32 chunks of 2 rows (1 KB each); swizzle source col by row&7
    {
        int rin = lane >> 5;                 // row within 2-row chunk
        int slot = lane & 31;
#pragma unroll
        for (int i = 0; i < 4; ++i) {
            int c = (w << 2) + i;
            int r = (c << 1) + rin;
            int src_col = ((slot ^ (r & 7)) << 3);
            ASYNC16(As + (c << 9), Aln + (size_t)(row0 + r) * 256 + src_col);
        }
    }
    __syncthreads();

    f32x4 oacc[4][2];
#pragma unroll
    for (int mf = 0; mf < 4; ++mf)
#pragma unroll
        for (int nf = 0; nf < 2; ++nf) oacc[mf][nf] = (f32x4){0.f, 0.f, 0.f, 0.f};

    for (int hk = 0; hk < 8; ++hk) {
        const int hc0 = hk << 7;
        // ---- GEMM1: P[64 tok][16 hid(this wave)] = A @ W1^T ----
        f32x4 pacc[4];
#pragma unroll
        for (int mf = 0; mf < 4; ++mf) pacc[mf] = (f32x4){0.f, 0.f, 0.f, 0.f};
        const ushort* w1p = W1 + (size_t)(hc0 + w * 16 + lr) * 256 + lg * 8;
#pragma unroll
        for (int ks = 0; ks < 8; ++ks) {
            bf16x8 bW = *(const bf16x8*)(w1p + ks * 32);
#pragma unroll
            for (int mf = 0; mf < 4; ++mf) {
                bf16x8 aA = *(const bf16x8*)(As + (mf * 16 + lr) * 256 + ((ks * 32 + lg * 8) ^ rxor));
                pacc[mf] = __builtin_amdgcn_mfma_f32_16x16x32_bf16(aA, bW, pacc[mf], 0, 0, 0);
            }
        }
        if (hk) __syncthreads();            // prev chunk's Ps reads done
        float hb = b1[hc0 + w * 16 + lr];
        int hcol = w * 16 + lr;
#pragma unroll
        for (int mf = 0; mf < 4; ++mf)
#pragma unroll
            for (int i = 0; i < 4; ++i) {
                int row = mf * 16 + lg * 4 + i;
                float v = pacc[mf][i] + hb;
                float gl = 0.5f * v * (1.0f + erff(v * 0.70710678118f));
                int col_sw = ((((hcol >> 3) ^ (row & 7)) << 3) | (hcol & 7));
                Ps[row * 128 + col_sw] = f2b(gl);
            }
        __syncthreads();
        // ---- GEMM2: oacc += P @ W2^T (this wave: out cols w*32..w*32+32) ----
        const ushort* w2p = W2 + (size_t)(w * 32 + lr) * 1024 + hc0 + lg * 8;
#pragma unroll
        for (int ks = 0; ks < 4; ++ks) {
            bf16x8 pA[4];
#pragma unroll
            for (int mf = 0; mf < 4; ++mf)
                pA[mf] = *(const bf16x8*)(Ps + (mf * 16 + lr) * 128 + ((ks * 32 + lg * 8) ^ rxor));
            bf16x8 w2f0 = *(const bf16x8*)(w2p + ks * 32);
            bf16x8 w2f1 = *(const bf16x8*)(w2p + 16 * 1024 + ks * 32);
#pragma unroll
            for (int mf = 0; mf < 4; ++mf) {
                oacc[mf][0] = __builtin_amdgcn_mfma_f32_16x16x32_bf16(pA[mf], w2f0, oacc[mf][0], 0, 0, 0);
                oacc[mf][1] = __builtin_amdgcn_mfma_f32_16x16x32_bf16(pA[mf], w2f1, oacc[mf][1], 0, 0, 0);
            }
        }
    }
    // epilogue: + b2 + R, write NCHW fp32
#pragma unroll
    for (int nf = 0; nf < 2; ++nf) {
        int f = w * 32 + nf * 16 + lr;
        float bb = b2[f];
#pragma unroll
        for (int mf = 0; mf < 4; ++mf)
#pragma unroll
            for (int i = 0; i < 4; ++i) {
                int t = row0 + mf * 16 + lg * 4 + i;
                float v = oacc[mf][nf][i] + bb + R[(size_t)t * 256 + f];
                out[((size_t)(t >> 12) * 256 + f) * 4096 + (t & 4095)] = v;
            }
    }
}

// ---------------- depthwise 3x3 + BN2, 4 pixels/thread (token-major bf16) ----------------
__global__ __launch_bounds__(256)
void k_dwconv(const ushort* __restrict__ Hin, const float* __restrict__ wT,
              const float* __restrict__ bf, ushort* __restrict__ Out) {
    int tid = threadIdx.x;
    int pg = blockIdx.x * 8 + (tid >> 5);
    int c0 = (tid & 31) << 3;
    int p0 = pg << 2;                  // 4 consecutive pixels, same row
    int b12 = p0 & ~4095;
    int hw = p0 & 4095, h0 = hw >> 6, w0 = hw & 63;

    float wreg[9][8];
#pragma unroll
    for (int k = 0; k < 9; ++k) {
        f32x4 a = *(const f32x4*)(wT + k * 256 + c0);
        f32x4 bq = *(const f32x4*)(wT + k * 256 + c0 + 4);
        wreg[k][0] = a.x; wreg[k][1] = a.y; wreg[k][2] = a.z; wreg[k][3] = a.w;
        wreg[k][4] = bq.x; wreg[k][5] = bq.y; wreg[k][6] = bq.z; wreg[k][7] = bq.w;
    }
    float acc[4][8];
    {
        f32x4 b0 = *(const f32x4*)(bf + c0), b1 = *(const f32x4*)(bf + c0 + 4);
#pragma unroll
        for (int px = 0; px < 4; ++px) {
            acc[px][0] = b0.x; acc[px][1] = b0.y; acc[px][2] = b0.z; acc[px][3] = b0.w;
            acc[px][4] = b1.x; acc[px][5] = b1.y; acc[px][6] = b1.z; acc[px][7] = b1.w;
        }
    }
#pragma unroll
    for (int dy = -1; dy <= 1; ++dy) {
        int hy = h0 + dy;
        if ((unsigned)hy >= 64u) continue;
        const ushort* rp = Hin + (((size_t)(b12 + (hy << 6))) << 8) + c0;
#pragma unroll
        for (int dx = -1; dx <= 4; ++dx) {
            int col = w0 + dx;
            if ((unsigned)col >= 64u) continue;
            bf16x8 v = *(const bf16x8*)(rp + ((size_t)col << 8));
            float vf[8];
#pragma unroll
            for (int j = 0; j < 8; ++j) vf[j] = b2f((ushort)v[j]);
#pragma unroll
            for (int px = 0; px < 4; ++px) {
                int kx = dx - px + 1;
                if (kx < 0 || kx > 2) continue;
                int k = (dy + 1) * 3 + kx;
#pragma unroll
                for (int j = 0; j < 8; ++j) acc[px][j] += vf[j] * wreg[k][j];
            }
        }
    }
#pragma unroll
    for (int px = 0; px < 4; ++px) {
        bf16x8 o;
#pragma unroll
        for (int j = 0; j < 8; ++j) o[j] = (short)f2b(acc[px][j]);
        *(bf16x8*)(Out + (size_t)(p0 + px) * 256 + c0) = o;
    }
}

// ---------------- LayerNorm over C=256 (one wave per token), fp32 in -> bf16 out ----------------
__global__ __launch_bounds__(256)
void k_ln(const float* __restrict__ R, const float* __restrict__ g,
          const float* __restrict__ be, ushort* __restrict__ O) {
    int lane = threadIdx.x & 63;
    size_t t = (size_t)blockIdx.x * 4 + (threadIdx.x >> 6);
    f32x4 v = *(const f32x4*)(R + t * 256 + lane * 4);
    float s = v.x + v.y + v.z + v.w;
    float q = v.x * v.x + v.y * v.y + v.z * v.z + v.w * v.w;
#pragma unroll
    for (int m = 1; m < 64; m <<= 1) { s += __shfl_xor(s, m, 64); q += __shfl_xor(q, m, 64); }
    float mu = s * (1.f / 256.f);
    float rs = rsqrtf(q * (1.f / 256.f) - mu * mu + EPS);
    int c = lane * 4;
    f32x4 gv = *(const f32x4*)(g + c), bv = *(const f32x4*)(be + c);
    s16x4 o;
    o[0] = (short)f2b((v.x - mu) * rs * gv.x + bv.x);
    o[1] = (short)f2b((v.y - mu) * rs * gv.y + bv.y);
    o[2] = (short)f2b((v.z - mu) * rs * gv.z + bv.z);
    o[3] = (short)f2b((v.w - mu) * rs * gv.w + bv.w);
    *(s16x4*)(O + t * 256 + c) = o;
}

// ---------------- windowed attention, MFMA version ----------------
__global__ __launch_bounds__(256)
void k_attn(const ushort* __restrict__ QKV, ushort* __restrict__ O) {
    __shared__ ushort SH[4][64 * 68];
    const int tid = threadIdx.x;
    const int w = tid >> 6, lane = tid & 63;
    const int lr = lane & 15, lg = lane >> 4;
    const int win = blockIdx.x;
    const int b = win >> 6, wh = (win >> 3) & 7, ww = win & 7;
    const int rowbase = (b << 12) + (wh << 9) + (ww << 3);
    const int h = w;

#define TROW(tok) (rowbase + (((tok) >> 3) << 6) + ((tok) & 7))

    bf16x8 qB[4][2], kA[4][2], vR[8];
#pragma unroll
    for (int f = 0; f < 4; ++f) {
        size_t t = (size_t)TROW(f * 16 + lr);
        const ushort* qp = QKV + t * 768 + h * 64 + lg * 8;
#pragma unroll
        for (int ks = 0; ks < 2; ++ks) {
            qB[f][ks] = *(const bf16x8*)(qp + ks * 32);
            kA[f][ks] = *(const bf16x8*)(qp + 256 + ks * 32);
        }
    }
    {
        size_t t = (size_t)TROW(lane);
        const ushort* vp = QKV + t * 768 + 512 + h * 64;
#pragma unroll
        for (int i = 0; i < 8; ++i) vR[i] = *(const bf16x8*)(vp + i * 8);
    }

    f32x4 st[4][4];
#pragma unroll
    for (int kf = 0; kf < 4; ++kf)
#pragma unroll
        for (int qf = 0; qf < 4; ++qf) st[kf][qf] = (f32x4){0.f, 0.f, 0.f, 0.f};
#pragma unroll
    for (int ks = 0; ks < 2; ++ks)
#pragma unroll
        for (int kf = 0; kf < 4; ++kf)
#pragma unroll
            for (int qf = 0; qf < 4; ++qf)
                st[kf][qf] = __builtin_amdgcn_mfma_f32_16x16x32_bf16(kA[kf][ks], qB[qf][ks], st[kf][qf], 0, 0, 0);

    ushort* P = &SH[w][0];
#pragma unroll
    for (int qf = 0; qf < 4; ++qf) {
        float m = -1e30f;
#pragma unroll
        for (int kf = 0; kf < 4; ++kf)
#pragma unroll
            for (int i = 0; i < 4; ++i) m = fmaxf(m, st[kf][qf][i]);
        m = fmaxf(m, __shfl_xor(m, 16, 64));
        m = fmaxf(m, __shfl_xor(m, 32, 64));
        m *= 0.125f;
        float sum = 0.f;
#pragma unroll
        for (int kf = 0; kf < 4; ++kf) {
            f32x4 e;
#pragma unroll
            for (int i = 0; i < 4; ++i) { e[i] = __expf(st[kf][qf][i] * 0.125f - m); sum += e[i]; }
            st[kf][qf] = e;
        }
        sum += __shfl_xor(sum, 16, 64);
        sum += __shfl_xor(sum, 32, 64);
        float rl = 1.f / sum;
#pragma unroll
        for (int kf = 0; kf < 4; ++kf) {
            s16x4 pk;
#pragma unroll
            for (int i = 0; i < 4; ++i) pk[i] = (short)f2b(st[kf][qf][i] * rl);
            *(s16x4*)(P + (qf * 16 + lr) * 68 + kf * 16 + lg * 4) = pk;
        }
    }
    bf16x8 pA[4][2];
#pragma unroll
    for (int mf = 0; mf < 4; ++mf)
#pragma unroll
        for (int ks = 0; ks < 2; ++ks) {
            union { bf16x8 v8; s16x4 v4[2]; } u;
            const ushort* p = P + (mf * 16 + lr) * 68 + ks * 32 + lg * 8;
            u.v4[0] = *(const s16x4*)(p);
            u.v4[1] = *(const s16x4*)(p + 4);
            pA[mf][ks] = u.v8;
        }
    asm volatile("s_waitcnt lgkmcnt(0)" ::: "memory");
    __builtin_amdgcn_sched_barrier(0);
#pragma unroll
    for (int i = 0; i < 8; ++i) {
        union { bf16x8 v8; s16x4 v4[2]; } u; u.v8 = vR[i];
        *(s16x4*)(P + lane * 68 + i * 8) = u.v4[0];
        *(s16x4*)(P + lane * 68 + i * 8 + 4) = u.v4[1];
    }
    asm volatile("s_waitcnt lgkmcnt(0)" ::: "memory");
    __builtin_amdgcn_sched_barrier(0);
    bf16x8 vB[4][2];
#pragma unroll
    for (int nf = 0; nf < 4; ++nf)
#pragma unroll
        for (int ks = 0; ks < 2; ++ks) {
            bf16x8 vb;
#pragma unroll
            for (int j = 0; j < 8; ++j)
                vb[j] = (short)P[(ks * 32 + lg * 8 + j) * 68 + nf * 16 + lr];
            vB[nf][ks] = vb;
        }
    f32x4 o[4][4];
#pragma unroll
    for (int mf = 0; mf < 4; ++mf)
#pragma unroll
        for (int nf = 0; nf < 4; ++nf) o[mf][nf] = (f32x4){0.f, 0.f, 0.f, 0.f};
#pragma unroll
    for (int ks = 0; ks < 2; ++ks)
#pragma unroll
        for (int mf = 0; mf < 4; ++mf)
#pragma unroll
            for (int nf = 0; nf < 4; ++nf)
                o[mf][nf] = __builtin_amdgcn_mfma_f32_16x16x32_bf16(pA[mf][ks], vB[nf][ks], o[mf][nf], 0, 0, 0);
#pragma unroll
    for (int mf = 0; mf < 4; ++mf)
#pragma unroll
        for (int nf = 0; nf < 4; ++nf)
#pragma unroll
            for (int i = 0; i < 4; ++i) {
                int q = mf * 16 + lg * 4 + i;
                int d = nf * 16 + lr;
                O[(size_t)TROW(q) * 256 + h * 64 + d] = f2b(o[mf][nf][i]);
            }
#undef TROW
}

extern "C" void kernel_launch(void* const* d_in, const int* in_sizes, int n_in,
                              void* d_out, int out_size, void* d_ws, size_t ws_size,
                              hipStream_t stream) {
    const float* x       = (const float*)d_in[0];
    const float* conv1_w = (const float*)d_in[1];
    const float* conv1_b = (const float*)d_in[2];
    const float* bn1_g   = (const float*)d_in[3];
    const float* bn1_b   = (const float*)d_in[4];
    const float* bn1_m   = (const float*)d_in[5];
    const float* bn1_v   = (const float*)d_in[6];
    const float* dw_w    = (const float*)d_in[7];
    const float* dw_b    = (const float*)d_in[8];
    const float* bn2_g   = (const float*)d_in[9];
    const float* bn2_b   = (const float*)d_in[10];
    const float* bn2_m   = (const float*)d_in[11];
    const float* bn2_v   = (const float*)d_in[12];
    const float* conv3_w = (const float*)d_in[13];
    const float* conv3_b = (const float*)d_in[14];
    const float* ln1_g   = (const float*)d_in[15];
    const float* ln1_b   = (const float*)d_in[16];
    const float* qkv_w   = (const float*)d_in[17];
    const float* qkv_b   = (const float*)d_in[18];
    const float* proj_w  = (const float*)d_in[19];
    const float* proj_b  = (const float*)d_in[20];
    const float* ln2_g   = (const float*)d_in[21];
    const float* ln2_b   = (const float*)d_in[22];
    const float* mlp_w1  = (const float*)d_in[23];
    const float* mlp_b1  = (const float*)d_in[24];
    const float* mlp_w2  = (const float*)d_in[25];
    const float* mlp_b2  = (const float*)d_in[26];
    float* out = (float*)d_out;

    char* ws = (char*)d_ws;
    float*  R    = (float*)(ws);                          // 64 MB fp32 residual stream [t][256]
    ushort* Abuf = (ushort*)(ws + (64u  << 20));          // 32 MB bf16 [t][256]
    ushort* H1   = (ushort*)(ws + (96u  << 20));          // 32 MB bf16 [t][256]
    ushort* BIG  = (ushort*)(ws + (128u << 20));          // 96 MB bf16: QKV [t][768]
    char* wp = ws + (224u << 20);
    ushort* W1f  = (ushort*)wp; wp += 131072;
    float*  b1f  = (float*)wp;  wp += 1024;
    float*  wdwT = (float*)wp;  wp += 9216;
    float*  bdw  = (float*)wp;  wp += 1024;
    ushort* W3   = (ushort*)wp; wp += 131072;
    ushort* Wqkv = (ushort*)wp; wp += 393216;
    ushort* Wproj= (ushort*)wp; wp += 131072;
    ushort* Wm1  = (ushort*)wp; wp += 524288;
    ushort* Wm2  = (ushort*)wp; wp += 524288;

    // weight prep (tiny)
    k_fold_conv1<<<256, 256, 0, stream>>>(conv1_w, conv1_b, bn1_g, bn1_b, bn1_m, bn1_v, W1f, b1f);
    k_fold_dw<<<9, 256, 0, stream>>>(dw_w, dw_b, bn2_g, bn2_b, bn2_m, bn2_v, wdwT, bdw);
    k_cvt_bf16<<<256, 256, 0, stream>>>(conv3_w, W3, 65536);
    k_cvt_bf16<<<768, 256, 0, stream>>>(qkv_w, Wqkv, 196608);
    k_cvt_bf16<<<256, 256, 0, stream>>>(proj_w, Wproj, 65536);
    k_cvt_bf16<<<1024, 256, 0, stream>>>(mlp_w1, Wm1, 262144);
    k_cvt_bf16<<<1024, 256, 0, stream>>>(mlp_w2, Wm2, 262144);

    // NCHW -> token-major
    k_transpose_in<<<dim3(128, 8, 16), 256, 0, stream>>>(x, R, Abuf);

    // conv path
    k_gemm_nt<0><<<dim3(512, 2), 256, 0, stream>>>(Abuf, W1f, b1f, H1, nullptr, 65536, 256, 256, 256);
    k_dwconv<<<2048, 256, 0, stream>>>(H1, wdwT, bdw, Abuf);
    k_gemm_nt<2><<<dim3(512, 2), 256, 0, stream>>>(Abuf, W3, conv3_b, nullptr, R, 65536, 256, 256, 256);

    // attention
    k_ln<<<16384, 256, 0, stream>>>(R, ln1_g, ln1_b, Abuf);
    k_gemm_nt<0><<<dim3(512, 6), 256, 0, stream>>>(Abuf, Wqkv, qkv_b, BIG, nullptr, 65536, 768, 256, 256);
    k_attn<<<1024, 256, 0, stream>>>(BIG, H1);
    k_gemm_nt<2><<<dim3(512, 2), 256, 0, stream>>>(H1, Wproj, proj_b, nullptr, R, 65536, 256, 256, 256);

    // FFN: fused MLP (no materialized hidden, no out RMW)
    k_ln<<<16384, 256, 0, stream>>>(R, ln2_g, ln2_b, Abuf);
    k_mlp<<<1024, 512, 0, stream>>>(Abuf, Wm1, mlp_b1, Wm2, mlp_b2, R, out);
}